// Round 1
// baseline (883.644 us; speedup 1.0000x reference)
//
#include <hip/hip_runtime.h>
#include <math.h>

// ---------------- constants from the reference ----------------
constexpr int IN_F  = 64;
constexpr int HID_F = 64;
constexpr int OUT_F = 32;
constexpr int NEXP  = 8;
constexpr int EMB   = 64;   // emb_dim
// N, E, B, E2 derived from in_sizes at launch.

// ---------------- utility kernels ----------------
__global__ void zero_kernel(float* __restrict__ p, long long n) {
    long long i = (long long)blockIdx.x * blockDim.x + threadIdx.x;
    long long stride = (long long)gridDim.x * blockDim.x;
    for (; i < n; i += stride) p[i] = 0.0f;
}

__global__ void deg_kernel(const int* __restrict__ dst, float* __restrict__ deg, int E) {
    int e = blockIdx.x * blockDim.x + threadIdx.x;
    if (e >= E) return;
    atomicAdd(&deg[dst[e]], 1.0f);
}

__global__ void rsqrt_kernel(float* __restrict__ d, int n) {
    int i = blockIdx.x * blockDim.x + threadIdx.x;
    if (i >= n) return;
    d[i] = rsqrtf(d[i] + 1.0f);
}

// ---------------- GEMM (x @ W) fused with self-loop init ----------------
// h[row,c] = dinv[row]^2 * (x@W)[row,c] + b[c];  xw[row,c] = (x@W)[row,c]
template<int CIN, int COUT, int ROWS>
__global__ __launch_bounds__(ROWS * COUT)
void gemm_selfloop_kernel(const float* __restrict__ x, const float* __restrict__ W,
                          const float* __restrict__ b, const float* __restrict__ dinv,
                          float* __restrict__ xw, float* __restrict__ h, int n)
{
    __shared__ float Ws[CIN * COUT];
    __shared__ float xs[ROWS * CIN];
    const int NT = ROWS * COUT;
    const int tid = threadIdx.x;

    for (int i = tid; i < CIN * COUT; i += NT) Ws[i] = W[i];
    const int row0 = blockIdx.x * ROWS;
    for (int i = tid; i < ROWS * CIN; i += NT) {
        int r = i / CIN;
        int rr = row0 + r;
        xs[i] = (rr < n) ? x[(size_t)rr * CIN + (i % CIN)] : 0.0f;
    }
    __syncthreads();

    const int r = tid / COUT;
    const int c = tid % COUT;
    const int row = row0 + r;
    if (row >= n) return;

    float acc = 0.0f;
#pragma unroll
    for (int k = 0; k < CIN; ++k) acc += xs[r * CIN + k] * Ws[k * COUT + c];

    xw[(size_t)row * COUT + c] = acc;
    float di = dinv[row];
    h[(size_t)row * COUT + c] = di * di * acc + b[c];
}

// ---------------- edge scatter-aggregate ----------------
// h[dst] += xw[src] * dinv[src] * dinv[dst]
template<int F>
__global__ void edge_agg_kernel(const int* __restrict__ src, const int* __restrict__ dst,
                                const float* __restrict__ dinv, const float* __restrict__ xw,
                                float* __restrict__ h, int E)
{
    long long t = (long long)blockIdx.x * blockDim.x + threadIdx.x;
    int e = (int)(t / F);
    int f = (int)(t % F);
    if (e >= E) return;
    int s = src[e];
    int d = dst[e];
    float norm = dinv[s] * dinv[d];
    atomicAdd(&h[(size_t)d * F + f], xw[(size_t)s * F + f] * norm);
}

// ---------------- mean pool ----------------
__global__ void pool_sum_kernel(const float* __restrict__ h, const int* __restrict__ batch,
                                float* __restrict__ pooled, float* __restrict__ cnt, int n)
{
    int t = blockIdx.x * blockDim.x + threadIdx.x;
    int i = t >> 5;          // node
    int f = t & 31;          // feature (OUT_F == 32)
    if (i >= n) return;
    int g = batch[i];
    atomicAdd(&pooled[(size_t)g * OUT_F + f], h[(size_t)i * OUT_F + f]);
    if (f == 0) atomicAdd(&cnt[g], 1.0f);
}

__global__ void pool_div_kernel(float* __restrict__ pooled, const float* __restrict__ cnt, int B)
{
    int t = blockIdx.x * blockDim.x + threadIdx.x;
    if (t >= B * OUT_F) return;
    int g = t >> 5;
    pooled[t] /= fmaxf(cnt[g], 1.0f);
}

// ---------------- gate: softmax([p0|p1] @ Wc + bc) ----------------
__global__ void gate_kernel(const float* __restrict__ p0, const float* __restrict__ p1,
                            const float* __restrict__ Wc, const float* __restrict__ bc,
                            float* __restrict__ gate, int B)
{
    int g = blockIdx.x * blockDim.x + threadIdx.x;
    if (g >= B) return;
    float xv[2 * OUT_F];
#pragma unroll
    for (int k = 0; k < OUT_F; ++k) xv[k] = p0[(size_t)g * OUT_F + k];
#pragma unroll
    for (int k = 0; k < OUT_F; ++k) xv[OUT_F + k] = p1[(size_t)g * OUT_F + k];

    float lg[NEXP];
    float m = -1e30f;
#pragma unroll
    for (int e = 0; e < NEXP; ++e) {
        float acc = bc[e];
#pragma unroll
        for (int k = 0; k < 2 * OUT_F; ++k) acc += xv[k] * Wc[k * NEXP + e];
        lg[e] = acc;
        m = fmaxf(m, acc);
    }
    float se = 0.0f;
#pragma unroll
    for (int e = 0; e < NEXP; ++e) { lg[e] = expf(lg[e] - m); se += lg[e]; }
    float inv = 1.0f / se;
#pragma unroll
    for (int e = 0; e < NEXP; ++e) gate[(size_t)g * NEXP + e] = lg[e] * inv;
}

__global__ void zero_scalar_kernel(float* p) { *p = 0.0f; }

// ---------------- distortion loss ----------------
// wave (64 lanes) per edge; lane l handles embedding element j*64+l for expert j
__global__ void distortion_kernel(const float* __restrict__ emb, const float* __restrict__ gate,
                                  const float* __restrict__ dis,
                                  const int* __restrict__ s_idx, const int* __restrict__ d_idx,
                                  float* __restrict__ loss, int E2)
{
    int gt = blockIdx.x * blockDim.x + threadIdx.x;
    int wid = gt >> 6;
    int lane = threadIdx.x & 63;
    int nw = (gridDim.x * blockDim.x) >> 6;

    float lsum = 0.0f;
    for (int e = wid; e < E2; e += nw) {
        int s = s_idx[e];
        int d = d_idx[e];
        const float* es = emb + (size_t)s * (NEXP * EMB);
        const float* ed = emb + (size_t)d * (NEXP * EMB);

        float diffk[NEXP];
#pragma unroll
        for (int j = 0; j < NEXP; ++j) {
            float a = es[j * EMB + lane];
            float b = ed[j * EMB + lane];
            float v = (a - b) * (a - b);
#pragma unroll
            for (int off = 32; off >= 1; off >>= 1) v += __shfl_xor(v, off);
            diffk[j] = v;   // identical on all lanes now
        }

        float gp[NEXP];
        float m = -1e30f;
#pragma unroll
        for (int j = 0; j < NEXP; ++j) {
            gp[j] = gate[(size_t)s * NEXP + j] * gate[(size_t)d * NEXP + j];
            m = fmaxf(m, gp[j]);
        }
        float se = 0.0f;
#pragma unroll
        for (int j = 0; j < NEXP; ++j) { gp[j] = expf(gp[j] - m); se += gp[j]; }
        float dsum = 0.0f;
#pragma unroll
        for (int j = 0; j < NEXP; ++j) dsum += diffk[j] * gp[j];
        dsum /= se;

        lsum += fabsf(dsum / dis[e] - 1.0f);
    }
    // lsum is identical across all 64 lanes of the wave
    if (lane == 0) atomicAdd(loss, lsum / (float)E2);
}

// ---------------- launch ----------------
extern "C" void kernel_launch(void* const* d_in, const int* in_sizes, int n_in,
                              void* d_out, int out_size, void* d_ws, size_t ws_size,
                              hipStream_t stream)
{
    const float* x0   = (const float*)d_in[0];
    const float* x1   = (const float*)d_in[1];
    const float* W1   = (const float*)d_in[2];
    const float* b1   = (const float*)d_in[3];
    const float* W2   = (const float*)d_in[4];
    const float* b2   = (const float*)d_in[5];
    const float* Wc   = (const float*)d_in[6];
    const float* bc   = (const float*)d_in[7];
    const float* emb  = (const float*)d_in[8];
    const float* dis  = (const float*)d_in[9];
    const int*   ei0  = (const int*)d_in[10];
    const int*   ei1  = (const int*)d_in[11];
    const int*   bat0 = (const int*)d_in[12];
    const int*   bat1 = (const int*)d_in[13];
    const int*   ei2  = (const int*)d_in[14];

    const int N  = in_sizes[0] / IN_F;
    const int E  = in_sizes[10] / 2;
    const int B  = in_sizes[8] / (NEXP * EMB);
    const int E2 = in_sizes[14] / 2;

    float* gate_out = (float*)d_out;              // B*NEXP
    float* loss_out = gate_out + (size_t)B * NEXP; // 1

    // workspace layout (floats)
    float* ws      = (float*)d_ws;
    float* dinv    = ws;                         // N
    float* bufA    = dinv + N;                   // N*64  (xw1; then xw2|h2)
    float* bufB    = bufA + (size_t)N * 64;      // N*64  (h1)
    float* pooled0 = bufB + (size_t)N * 64;      // B*32
    float* pooled1 = pooled0 + (size_t)B * OUT_F;// B*32
    float* cnt     = pooled1 + (size_t)B * OUT_F;// B

    const int TB = 256;
    const int zgrid = 1024;

    for (int g = 0; g < 2; ++g) {
        const float* x    = (g == 0) ? x0 : x1;
        const int* src    = (g == 0) ? ei0 : ei1;
        const int* dst    = src + E;
        const int* batch  = (g == 0) ? bat0 : bat1;
        float* pooled     = (g == 0) ? pooled0 : pooled1;

        float* xw1 = bufA;
        float* h1  = bufB;
        float* xw2 = bufA;                    // reuse (xw1 dead after conv1 agg)
        float* h2  = bufA + (size_t)N * OUT_F;

        // degree -> dinv
        zero_kernel<<<zgrid, TB, 0, stream>>>(dinv, N);
        deg_kernel<<<(E + TB - 1) / TB, TB, 0, stream>>>(dst, dinv, E);
        rsqrt_kernel<<<(N + TB - 1) / TB, TB, 0, stream>>>(dinv, N);

        // conv1: 64 -> 64
        gemm_selfloop_kernel<IN_F, HID_F, 4>
            <<<(N + 3) / 4, 4 * HID_F, 0, stream>>>(x, W1, b1, dinv, xw1, h1, N);
        {
            long long threads = (long long)E * HID_F;
            edge_agg_kernel<HID_F>
                <<<(int)((threads + TB - 1) / TB), TB, 0, stream>>>(src, dst, dinv, xw1, h1, E);
        }

        // conv2: 64 -> 32
        gemm_selfloop_kernel<HID_F, OUT_F, 8>
            <<<(N + 7) / 8, 8 * OUT_F, 0, stream>>>(h1, W2, b2, dinv, xw2, h2, N);
        {
            long long threads = (long long)E * OUT_F;
            edge_agg_kernel<OUT_F>
                <<<(int)((threads + TB - 1) / TB), TB, 0, stream>>>(src, dst, dinv, xw2, h2, E);
        }

        // mean pool
        zero_kernel<<<zgrid, TB, 0, stream>>>(pooled, (long long)B * OUT_F);
        zero_kernel<<<zgrid, TB, 0, stream>>>(cnt, B);
        pool_sum_kernel<<<((N * 32) + TB - 1) / TB, TB, 0, stream>>>(h2, batch, pooled, cnt, N);
        pool_div_kernel<<<((B * OUT_F) + TB - 1) / TB, TB, 0, stream>>>(pooled, cnt, B);
    }

    // gate
    gate_kernel<<<(B + TB - 1) / TB, TB, 0, stream>>>(pooled0, pooled1, Wc, bc, gate_out, B);

    // distortion loss
    zero_scalar_kernel<<<1, 1, 0, stream>>>(loss_out);
    distortion_kernel<<<1024, TB, 0, stream>>>(emb, gate_out, dis,
                                               ei2, ei2 + E2, loss_out, E2);
}

// Round 2
// 745.605 us; speedup vs baseline: 1.1851x; 1.1851x over previous
//
#include <hip/hip_runtime.h>
#include <math.h>

// ---------------- constants from the reference ----------------
constexpr int IN_F  = 64;
constexpr int HID_F = 64;
constexpr int OUT_F = 32;
constexpr int NEXP  = 8;
constexpr int EMB   = 64;   // emb_dim

// ---------------- utility kernels ----------------
__global__ void zero_f32_kernel(float* __restrict__ p, long long n) {
    long long i = (long long)blockIdx.x * blockDim.x + threadIdx.x;
    long long stride = (long long)gridDim.x * blockDim.x;
    for (; i < n; i += stride) p[i] = 0.0f;
}

__global__ void zero_i32_kernel(int* __restrict__ p, long long n) {
    long long i = (long long)blockIdx.x * blockDim.x + threadIdx.x;
    long long stride = (long long)gridDim.x * blockDim.x;
    for (; i < n; i += stride) p[i] = 0;
}

// ---------------- CSR build ----------------
__global__ void hist_kernel(const int* __restrict__ dst, int* __restrict__ counts, int E) {
    int e = blockIdx.x * blockDim.x + threadIdx.x;
    if (e >= E) return;
    atomicAdd(&counts[dst[e]], 1);
}

__global__ void dinv_kernel(const int* __restrict__ counts, float* __restrict__ dinv, int n) {
    int i = blockIdx.x * blockDim.x + threadIdx.x;
    if (i >= n) return;
    dinv[i] = rsqrtf((float)counts[i] + 1.0f);
}

// single-block exclusive scan over counts -> offsets[N+1], also fills cursor[N]
__global__ __launch_bounds__(1024)
void scan_kernel(const int* __restrict__ counts, int* __restrict__ offsets,
                 int* __restrict__ cursor, int N)
{
    __shared__ int wsum[16];
    __shared__ int s_carry;
    const int tid  = threadIdx.x;
    const int lane = tid & 63;
    const int wv   = tid >> 6;
    if (tid == 0) s_carry = 0;
    __syncthreads();
    for (int base = 0; base < N; base += 1024) {
        int i = base + tid;
        int v = (i < N) ? counts[i] : 0;
        // inclusive wave scan
        int x = v;
#pragma unroll
        for (int off = 1; off < 64; off <<= 1) {
            int t = __shfl_up(x, off);
            if (lane >= off) x += t;
        }
        if (lane == 63) wsum[wv] = x;
        __syncthreads();
        int carry = s_carry;
        int woff = 0;
        for (int w = 0; w < 16; ++w) if (w < wv) woff += wsum[w];
        int excl = carry + woff + x - v;
        if (i < N) { offsets[i] = excl; cursor[i] = excl; }
        __syncthreads();
        if (tid == 0) {
            int tot = 0;
            for (int w = 0; w < 16; ++w) tot += wsum[w];
            s_carry = carry + tot;
        }
        __syncthreads();
    }
    if (tid == 0) offsets[N] = s_carry;
}

__global__ void scatter_kernel(const int* __restrict__ src, const int* __restrict__ dst,
                               int* __restrict__ cursor, int* __restrict__ csr_src, int E)
{
    int e = blockIdx.x * blockDim.x + threadIdx.x;
    if (e >= E) return;
    int d = dst[e];
    int pos = atomicAdd(&cursor[d], 1);
    csr_src[pos] = src[e];
}

// ---------------- GEMM (x @ W) fused with dinv pre-scale + self-loop init ----------------
// xws[row,c] = (x@W)[row,c] * dinv[row];  h[row,c] = dinv[row]*xws[row,c] + b[c]
template<int CIN, int COUT, int ROWS>
__global__ __launch_bounds__(ROWS * COUT)
void gemm_selfloop_kernel(const float* __restrict__ x, const float* __restrict__ W,
                          const float* __restrict__ b, const float* __restrict__ dinv,
                          float* __restrict__ xws, float* __restrict__ h, int n)
{
    __shared__ float Ws[CIN * COUT];
    __shared__ float xs[ROWS * CIN];
    const int NT = ROWS * COUT;
    const int tid = threadIdx.x;

    for (int i = tid; i < CIN * COUT; i += NT) Ws[i] = W[i];
    const int row0 = blockIdx.x * ROWS;
    for (int i = tid; i < ROWS * CIN; i += NT) {
        int r = i / CIN;
        int rr = row0 + r;
        xs[i] = (rr < n) ? x[(size_t)rr * CIN + (i % CIN)] : 0.0f;
    }
    __syncthreads();

    const int r = tid / COUT;
    const int c = tid % COUT;
    const int row = row0 + r;
    if (row >= n) return;

    float acc = 0.0f;
#pragma unroll
    for (int k = 0; k < CIN; ++k) acc += xs[r * CIN + k] * Ws[k * COUT + c];

    float di = dinv[row];
    float xv = acc * di;
    xws[(size_t)row * COUT + c] = xv;
    h[(size_t)row * COUT + c] = di * xv + b[c];
}

// ---------------- CSR gather-aggregate (no atomics) ----------------
// h[i] += dinv[i] * sum_{s in in(i)} xws[s]
template<int F>
__global__ __launch_bounds__(256)
void csr_agg_kernel(const int* __restrict__ csr_src, const int* __restrict__ offsets,
                    const float* __restrict__ xws, const float* __restrict__ dinv,
                    float* __restrict__ h, int n)
{
    constexpr int SUB = 64 / F;           // nodes per wave
    const int lane = threadIdx.x & 63;
    const int wid  = (blockIdx.x * (blockDim.x >> 6)) + (threadIdx.x >> 6);
    const int sub  = lane / F;
    const int f    = lane % F;
    const int node = wid * SUB + sub;

    const bool valid = (node < n);
    const int nc   = valid ? node : 0;
    const int off0 = offsets[nc];
    const int off1 = valid ? offsets[nc + 1] : off0;

    float acc = 0.0f;
    for (int k = off0; k < off1; k += F) {
        int nk = off1 - k; if (nk > F) nk = F;
        int sj = (f < nk) ? csr_src[k + f] : 0;
        for (int t = 0; t < nk; ++t) {
            int s = __shfl(sj, sub * F + t);
            acc += xws[(size_t)s * F + f];
        }
    }
    if (valid) h[(size_t)node * F + f] += dinv[node] * acc;
}

// ---------------- mean pool ----------------
__global__ void pool_sum_kernel(const float* __restrict__ h, const int* __restrict__ batch,
                                float* __restrict__ pooled, float* __restrict__ cnt, int n)
{
    int t = blockIdx.x * blockDim.x + threadIdx.x;
    int i = t >> 5;          // node
    int f = t & 31;          // feature (OUT_F == 32)
    if (i >= n) return;
    int g = batch[i];
    atomicAdd(&pooled[(size_t)g * OUT_F + f], h[(size_t)i * OUT_F + f]);
    if (f == 0) atomicAdd(&cnt[g], 1.0f);
}

__global__ void pool_div_kernel(float* __restrict__ pooled, const float* __restrict__ cnt, int B)
{
    int t = blockIdx.x * blockDim.x + threadIdx.x;
    if (t >= B * OUT_F) return;
    int g = t >> 5;
    pooled[t] /= fmaxf(cnt[g], 1.0f);
}

// ---------------- gate: softmax([p0|p1] @ Wc + bc) ----------------
__global__ void gate_kernel(const float* __restrict__ p0, const float* __restrict__ p1,
                            const float* __restrict__ Wc, const float* __restrict__ bc,
                            float* __restrict__ gate, int B)
{
    int g = blockIdx.x * blockDim.x + threadIdx.x;
    if (g >= B) return;
    float xv[2 * OUT_F];
#pragma unroll
    for (int k = 0; k < OUT_F; ++k) xv[k] = p0[(size_t)g * OUT_F + k];
#pragma unroll
    for (int k = 0; k < OUT_F; ++k) xv[OUT_F + k] = p1[(size_t)g * OUT_F + k];

    float lg[NEXP];
    float m = -1e30f;
#pragma unroll
    for (int e = 0; e < NEXP; ++e) {
        float acc = bc[e];
#pragma unroll
        for (int k = 0; k < 2 * OUT_F; ++k) acc += xv[k] * Wc[k * NEXP + e];
        lg[e] = acc;
        m = fmaxf(m, acc);
    }
    float se = 0.0f;
#pragma unroll
    for (int e = 0; e < NEXP; ++e) { lg[e] = expf(lg[e] - m); se += lg[e]; }
    float inv = 1.0f / se;
#pragma unroll
    for (int e = 0; e < NEXP; ++e) gate[(size_t)g * NEXP + e] = lg[e] * inv;
}

__global__ void zero_scalar_kernel(float* p) { *p = 0.0f; }

// ---------------- distortion loss ----------------
__global__ void distortion_kernel(const float* __restrict__ emb, const float* __restrict__ gate,
                                  const float* __restrict__ dis,
                                  const int* __restrict__ s_idx, const int* __restrict__ d_idx,
                                  float* __restrict__ loss, int E2)
{
    int gt = blockIdx.x * blockDim.x + threadIdx.x;
    int wid = gt >> 6;
    int lane = threadIdx.x & 63;
    int nw = (gridDim.x * blockDim.x) >> 6;

    float lsum = 0.0f;
    for (int e = wid; e < E2; e += nw) {
        int s = s_idx[e];
        int d = d_idx[e];
        const float* es = emb + (size_t)s * (NEXP * EMB);
        const float* ed = emb + (size_t)d * (NEXP * EMB);

        float diffk[NEXP];
#pragma unroll
        for (int j = 0; j < NEXP; ++j) {
            float a = es[j * EMB + lane];
            float b = ed[j * EMB + lane];
            float v = (a - b) * (a - b);
#pragma unroll
            for (int off = 32; off >= 1; off >>= 1) v += __shfl_xor(v, off);
            diffk[j] = v;
        }

        float gp[NEXP];
        float m = -1e30f;
#pragma unroll
        for (int j = 0; j < NEXP; ++j) {
            gp[j] = gate[(size_t)s * NEXP + j] * gate[(size_t)d * NEXP + j];
            m = fmaxf(m, gp[j]);
        }
        float se = 0.0f;
#pragma unroll
        for (int j = 0; j < NEXP; ++j) { gp[j] = expf(gp[j] - m); se += gp[j]; }
        float dsum = 0.0f;
#pragma unroll
        for (int j = 0; j < NEXP; ++j) dsum += diffk[j] * gp[j];
        dsum /= se;

        lsum += fabsf(dsum / dis[e] - 1.0f);
    }
    if (lane == 0) atomicAdd(loss, lsum / (float)E2);
}

// ---------------- launch ----------------
extern "C" void kernel_launch(void* const* d_in, const int* in_sizes, int n_in,
                              void* d_out, int out_size, void* d_ws, size_t ws_size,
                              hipStream_t stream)
{
    const float* x0   = (const float*)d_in[0];
    const float* x1   = (const float*)d_in[1];
    const float* W1   = (const float*)d_in[2];
    const float* b1   = (const float*)d_in[3];
    const float* W2   = (const float*)d_in[4];
    const float* b2   = (const float*)d_in[5];
    const float* Wc   = (const float*)d_in[6];
    const float* bc   = (const float*)d_in[7];
    const float* emb  = (const float*)d_in[8];
    const float* dis  = (const float*)d_in[9];
    const int*   ei0  = (const int*)d_in[10];
    const int*   ei1  = (const int*)d_in[11];
    const int*   bat0 = (const int*)d_in[12];
    const int*   bat1 = (const int*)d_in[13];
    const int*   ei2  = (const int*)d_in[14];

    const int N  = in_sizes[0] / IN_F;
    const int E  = in_sizes[10] / 2;
    const int B  = in_sizes[8] / (NEXP * EMB);
    const int E2 = in_sizes[14] / 2;

    float* gate_out = (float*)d_out;               // B*NEXP
    float* loss_out = gate_out + (size_t)B * NEXP; // 1

    // workspace layout
    float* ws      = (float*)d_ws;
    float* dinv    = ws;                           // N
    float* bufA    = dinv + N;                     // N*64  (xws1; then xws2|h2)
    float* bufB    = bufA + (size_t)N * 64;        // N*64  (h1)
    float* pooled0 = bufB + (size_t)N * 64;        // B*32
    float* pooled1 = pooled0 + (size_t)B * OUT_F;  // B*32
    float* cnt     = pooled1 + (size_t)B * OUT_F;  // B
    int*   iws     = (int*)(cnt + B);
    int*   counts  = iws;                          // N
    int*   offsets = counts + N;                   // N+1
    int*   cursor  = offsets + N + 1;              // N
    int*   csr_src = cursor + N;                   // E

    const int TB = 256;
    const int zgrid = 512;

    for (int g = 0; g < 2; ++g) {
        const float* x    = (g == 0) ? x0 : x1;
        const int* src    = (g == 0) ? ei0 : ei1;
        const int* dst    = src + E;
        const int* batch  = (g == 0) ? bat0 : bat1;
        float* pooled     = (g == 0) ? pooled0 : pooled1;

        float* xws1 = bufA;
        float* h1   = bufB;
        float* xws2 = bufA;                          // reuse (xws1 dead after agg1)
        float* h2   = bufA + (size_t)N * OUT_F;

        // CSR build (shared by both convs) + dinv
        zero_i32_kernel<<<zgrid, TB, 0, stream>>>(counts, N);
        hist_kernel<<<(E + TB - 1) / TB, TB, 0, stream>>>(dst, counts, E);
        dinv_kernel<<<(N + TB - 1) / TB, TB, 0, stream>>>(counts, dinv, N);
        scan_kernel<<<1, 1024, 0, stream>>>(counts, offsets, cursor, N);
        scatter_kernel<<<(E + TB - 1) / TB, TB, 0, stream>>>(src, dst, cursor, csr_src, E);

        // conv1: 64 -> 64
        gemm_selfloop_kernel<IN_F, HID_F, 4>
            <<<(N + 3) / 4, 4 * HID_F, 0, stream>>>(x, W1, b1, dinv, xws1, h1, N);
        csr_agg_kernel<HID_F>
            <<<(N + 3) / 4, TB, 0, stream>>>(csr_src, offsets, xws1, dinv, h1, N);

        // conv2: 64 -> 32
        gemm_selfloop_kernel<HID_F, OUT_F, 8>
            <<<(N + 7) / 8, 8 * OUT_F, 0, stream>>>(h1, W2, b2, dinv, xws2, h2, N);
        csr_agg_kernel<OUT_F>
            <<<(N + 7) / 8, TB, 0, stream>>>(csr_src, offsets, xws2, dinv, h2, N);

        // mean pool
        zero_f32_kernel<<<zgrid, TB, 0, stream>>>(pooled, (long long)B * OUT_F);
        zero_f32_kernel<<<zgrid, TB, 0, stream>>>(cnt, B);
        pool_sum_kernel<<<((N * 32) + TB - 1) / TB, TB, 0, stream>>>(h2, batch, pooled, cnt, N);
        pool_div_kernel<<<((B * OUT_F) + TB - 1) / TB, TB, 0, stream>>>(pooled, cnt, B);
    }

    // gate
    gate_kernel<<<(B + TB - 1) / TB, TB, 0, stream>>>(pooled0, pooled1, Wc, bc, gate_out, B);

    // distortion loss
    zero_scalar_kernel<<<1, 1, 0, stream>>>(loss_out);
    distortion_kernel<<<1024, TB, 0, stream>>>(emb, gate_out, dis,
                                               ei2, ei2 + E2, loss_out, E2);
}

// Round 3
// 620.775 us; speedup vs baseline: 1.4235x; 1.2011x over previous
//
#include <hip/hip_runtime.h>
#include <math.h>

// ---------------- constants from the reference ----------------
constexpr int IN_F  = 64;
constexpr int HID_F = 64;
constexpr int OUT_F = 32;
constexpr int NEXP  = 8;
constexpr int EMB   = 64;   // emb_dim

// ---------------- utility kernels ----------------
__global__ void zero_f32_kernel(float* __restrict__ p, long long n) {
    long long i = (long long)blockIdx.x * blockDim.x + threadIdx.x;
    long long stride = (long long)gridDim.x * blockDim.x;
    for (; i < n; i += stride) p[i] = 0.0f;
}

__global__ void zero_i32_kernel(int* __restrict__ p, long long n) {
    long long i = (long long)blockIdx.x * blockDim.x + threadIdx.x;
    long long stride = (long long)gridDim.x * blockDim.x;
    for (; i < n; i += stride) p[i] = 0;
}

// ---------------- CSR build ----------------
__global__ void hist_kernel(const int* __restrict__ dst, int* __restrict__ counts, int E) {
    int e = blockIdx.x * blockDim.x + threadIdx.x;
    if (e >= E) return;
    atomicAdd(&counts[dst[e]], 1);
}

// two-level exclusive scan (race-free)
// S1: per-block (1024 elems) local exclusive scan + block totals
__global__ __launch_bounds__(1024)
void scan1_kernel(const int* __restrict__ counts, int* __restrict__ lexcl,
                  int* __restrict__ partials, int N)
{
    __shared__ int wsum[16];
    const int tid  = threadIdx.x;
    const int lane = tid & 63;
    const int wv   = tid >> 6;
    const int i    = blockIdx.x * 1024 + tid;

    int v = (i < N) ? counts[i] : 0;
    int x = v;
#pragma unroll
    for (int off = 1; off < 64; off <<= 1) {
        int t = __shfl_up(x, off);
        if (lane >= off) x += t;
    }
    if (lane == 63) wsum[wv] = x;
    __syncthreads();
    int woff = 0;
    for (int w = 0; w < wv; ++w) woff += wsum[w];
    if (i < N) lexcl[i] = woff + x - v;
    if (tid == 1023) partials[blockIdx.x] = woff + x;   // block total
}

// S2: single-block exclusive scan of the block partials (NB <= 1024)
__global__ __launch_bounds__(1024)
void scan2_kernel(int* __restrict__ partials, int NB)
{
    __shared__ int wsum[16];
    const int tid  = threadIdx.x;
    const int lane = tid & 63;
    const int wv   = tid >> 6;
    int v = (tid < NB) ? partials[tid] : 0;
    int x = v;
#pragma unroll
    for (int off = 1; off < 64; off <<= 1) {
        int t = __shfl_up(x, off);
        if (lane >= off) x += t;
    }
    if (lane == 63) wsum[wv] = x;
    __syncthreads();
    int woff = 0;
    for (int w = 0; w < wv; ++w) woff += wsum[w];
    if (tid < NB) partials[tid] = woff + x - v;
}

// S3: combine -> offsets/cursor, plus dinv = rsqrt(deg+1)
__global__ void scan3_kernel(const int* __restrict__ lexcl, const int* __restrict__ partials,
                             const int* __restrict__ counts,
                             int* __restrict__ offsets, int* __restrict__ cursor,
                             float* __restrict__ dinv, int N, int E)
{
    int i = blockIdx.x * blockDim.x + threadIdx.x;
    if (i >= N) return;
    int o = lexcl[i] + partials[i >> 10];
    offsets[i] = o;
    cursor[i]  = o;
    dinv[i] = rsqrtf((float)counts[i] + 1.0f);
    if (i == 0) offsets[N] = E;
}

__global__ void scatter_kernel(const int* __restrict__ src, const int* __restrict__ dst,
                               int* __restrict__ cursor, int* __restrict__ csr_src, int E)
{
    int e = blockIdx.x * blockDim.x + threadIdx.x;
    if (e >= E) return;
    int d = dst[e];
    int pos = atomicAdd(&cursor[d], 1);
    csr_src[pos] = src[e];
}

// ---------------- GEMM (x @ W) fused with dinv pre-scale + self-loop init ----------------
// xws[row,c] = (x@W)[row,c] * dinv[row];  h[row,c] = dinv[row]*xws[row,c] + b[c]
template<int CIN, int COUT, int ROWS>
__global__ __launch_bounds__(ROWS * COUT)
void gemm_selfloop_kernel(const float* __restrict__ x, const float* __restrict__ W,
                          const float* __restrict__ b, const float* __restrict__ dinv,
                          float* __restrict__ xws, float* __restrict__ h, int n)
{
    __shared__ float Ws[CIN * COUT];
    __shared__ float xs[ROWS * CIN];
    const int NT = ROWS * COUT;
    const int tid = threadIdx.x;

    for (int i = tid; i < CIN * COUT; i += NT) Ws[i] = W[i];
    const int row0 = blockIdx.x * ROWS;
    for (int i = tid; i < ROWS * CIN; i += NT) {
        int r = i / CIN;
        int rr = row0 + r;
        xs[i] = (rr < n) ? x[(size_t)rr * CIN + (i % CIN)] : 0.0f;
    }
    __syncthreads();

    const int r = tid / COUT;
    const int c = tid % COUT;
    const int row = row0 + r;
    if (row >= n) return;

    float acc = 0.0f;
#pragma unroll
    for (int k = 0; k < CIN; ++k) acc += xs[r * CIN + k] * Ws[k * COUT + c];

    float di = dinv[row];
    float xv = acc * di;
    xws[(size_t)row * COUT + c] = xv;
    h[(size_t)row * COUT + c] = di * xv + b[c];
}

// ---------------- CSR gather-aggregate (no atomics) ----------------
// h[i] += dinv[i] * sum_{s in in(i)} xws[s]
template<int F>
__global__ __launch_bounds__(256)
void csr_agg_kernel(const int* __restrict__ csr_src, const int* __restrict__ offsets,
                    const float* __restrict__ xws, const float* __restrict__ dinv,
                    float* __restrict__ h, int n)
{
    constexpr int SUB = 64 / F;           // nodes per wave
    const int lane = threadIdx.x & 63;
    const int wid  = (blockIdx.x * (blockDim.x >> 6)) + (threadIdx.x >> 6);
    const int sub  = lane / F;
    const int f    = lane % F;
    const int node = wid * SUB + sub;
    const int lbase = sub * F;

    const bool valid = (node < n);
    const int nc   = valid ? node : 0;
    const int off0 = offsets[nc];
    const int off1 = valid ? offsets[nc + 1] : off0;

    float acc0 = 0.0f, acc1 = 0.0f;
    for (int k = off0; k < off1; k += F) {
        int nk = off1 - k; if (nk > F) nk = F;
        int sj = (f < nk) ? csr_src[k + f] : 0;
        int t = 0;
        for (; t + 4 <= nk; t += 4) {
            int s0 = __shfl(sj, lbase + t);
            int s1 = __shfl(sj, lbase + t + 1);
            int s2 = __shfl(sj, lbase + t + 2);
            int s3 = __shfl(sj, lbase + t + 3);
            float v0 = xws[(size_t)s0 * F + f];
            float v1 = xws[(size_t)s1 * F + f];
            float v2 = xws[(size_t)s2 * F + f];
            float v3 = xws[(size_t)s3 * F + f];
            acc0 += v0 + v2;
            acc1 += v1 + v3;
        }
        for (; t < nk; ++t) {
            int s = __shfl(sj, lbase + t);
            acc0 += xws[(size_t)s * F + f];
        }
    }
    if (valid) h[(size_t)node * F + f] += dinv[node] * (acc0 + acc1);
}

// ---------------- mean pool ----------------
__global__ void pool_sum_kernel(const float* __restrict__ h, const int* __restrict__ batch,
                                float* __restrict__ pooled, float* __restrict__ cnt, int n)
{
    int t = blockIdx.x * blockDim.x + threadIdx.x;
    int i = t >> 5;          // node
    int f = t & 31;          // feature (OUT_F == 32)
    if (i >= n) return;
    int g = batch[i];
    atomicAdd(&pooled[(size_t)g * OUT_F + f], h[(size_t)i * OUT_F + f]);
    if (f == 0) atomicAdd(&cnt[g], 1.0f);
}

__global__ void pool_div_kernel(float* __restrict__ pooled, const float* __restrict__ cnt, int B)
{
    int t = blockIdx.x * blockDim.x + threadIdx.x;
    if (t >= B * OUT_F) return;
    int g = t >> 5;
    pooled[t] /= fmaxf(cnt[g], 1.0f);
}

// ---------------- gate: softmax([p0|p1] @ Wc + bc) ----------------
__global__ void gate_kernel(const float* __restrict__ p0, const float* __restrict__ p1,
                            const float* __restrict__ Wc, const float* __restrict__ bc,
                            float* __restrict__ gate, int B)
{
    int g = blockIdx.x * blockDim.x + threadIdx.x;
    if (g >= B) return;
    float xv[2 * OUT_F];
#pragma unroll
    for (int k = 0; k < OUT_F; ++k) xv[k] = p0[(size_t)g * OUT_F + k];
#pragma unroll
    for (int k = 0; k < OUT_F; ++k) xv[OUT_F + k] = p1[(size_t)g * OUT_F + k];

    float lg[NEXP];
    float m = -1e30f;
#pragma unroll
    for (int e = 0; e < NEXP; ++e) {
        float acc = bc[e];
#pragma unroll
        for (int k = 0; k < 2 * OUT_F; ++k) acc += xv[k] * Wc[k * NEXP + e];
        lg[e] = acc;
        m = fmaxf(m, acc);
    }
    float se = 0.0f;
#pragma unroll
    for (int e = 0; e < NEXP; ++e) { lg[e] = expf(lg[e] - m); se += lg[e]; }
    float inv = 1.0f / se;
#pragma unroll
    for (int e = 0; e < NEXP; ++e) gate[(size_t)g * NEXP + e] = lg[e] * inv;
}

__global__ void zero_scalar_kernel(float* p) { *p = 0.0f; }

// ---------------- distortion loss ----------------
// wave per edge; lane l covers float4 elements [4l..4l+3] (expert l>>4) and
// [256+4l..256+4l+3] (expert 4+(l>>4)). 16-lane-group butterfly + 8-shfl gather.
__global__ __launch_bounds__(256)
void distortion_kernel(const float* __restrict__ emb, const float* __restrict__ gate,
                       const float* __restrict__ dis,
                       const int* __restrict__ s_idx, const int* __restrict__ d_idx,
                       float* __restrict__ loss, int E2)
{
    int gt = blockIdx.x * blockDim.x + threadIdx.x;
    int wid = gt >> 6;
    int lane = threadIdx.x & 63;
    int nw = (gridDim.x * blockDim.x) >> 6;

    const float4* emb4  = (const float4*)emb;
    const float4* gate4 = (const float4*)gate;

    float lsum = 0.0f;
    for (int e = wid; e < E2; e += nw) {
        int s = s_idx[e];
        int d = d_idx[e];
        const float4* es = emb4 + (size_t)s * 128;   // 512 floats = 128 float4
        const float4* ed = emb4 + (size_t)d * 128;

        float4 a0 = es[lane];
        float4 b0 = ed[lane];
        float4 a1 = es[lane + 64];
        float4 b1 = ed[lane + 64];

        float dx, pa, pb;
        dx = a0.x - b0.x; pa  = dx * dx;
        dx = a0.y - b0.y; pa += dx * dx;
        dx = a0.z - b0.z; pa += dx * dx;
        dx = a0.w - b0.w; pa += dx * dx;
        dx = a1.x - b1.x; pb  = dx * dx;
        dx = a1.y - b1.y; pb += dx * dx;
        dx = a1.z - b1.z; pb += dx * dx;
        dx = a1.w - b1.w; pb += dx * dx;

#pragma unroll
        for (int off = 1; off < 16; off <<= 1) {
            pa += __shfl_xor(pa, off);
            pb += __shfl_xor(pb, off);
        }
        // lane j*16 holds: pa = diff[expert j], pb = diff[expert 4+j]
        float dk[NEXP];
#pragma unroll
        for (int j = 0; j < 4; ++j) {
            dk[j]     = __shfl(pa, j * 16);
            dk[j + 4] = __shfl(pb, j * 16);
        }

        float4 gs0 = gate4[(size_t)s * 2];
        float4 gs1 = gate4[(size_t)s * 2 + 1];
        float4 gd0 = gate4[(size_t)d * 2];
        float4 gd1 = gate4[(size_t)d * 2 + 1];
        float gp[NEXP] = { gs0.x * gd0.x, gs0.y * gd0.y, gs0.z * gd0.z, gs0.w * gd0.w,
                           gs1.x * gd1.x, gs1.y * gd1.y, gs1.z * gd1.z, gs1.w * gd1.w };
        float m = gp[0];
#pragma unroll
        for (int j = 1; j < NEXP; ++j) m = fmaxf(m, gp[j]);
        float se = 0.0f;
#pragma unroll
        for (int j = 0; j < NEXP; ++j) { gp[j] = expf(gp[j] - m); se += gp[j]; }
        float dsum = 0.0f;
#pragma unroll
        for (int j = 0; j < NEXP; ++j) dsum += dk[j] * gp[j];
        dsum /= se;

        lsum += fabsf(dsum / dis[e] - 1.0f);
    }
    if (lane == 0) atomicAdd(loss, lsum / (float)E2);
}

// ---------------- launch ----------------
extern "C" void kernel_launch(void* const* d_in, const int* in_sizes, int n_in,
                              void* d_out, int out_size, void* d_ws, size_t ws_size,
                              hipStream_t stream)
{
    const float* x0   = (const float*)d_in[0];
    const float* x1   = (const float*)d_in[1];
    const float* W1   = (const float*)d_in[2];
    const float* b1   = (const float*)d_in[3];
    const float* W2   = (const float*)d_in[4];
    const float* b2   = (const float*)d_in[5];
    const float* Wc   = (const float*)d_in[6];
    const float* bc   = (const float*)d_in[7];
    const float* emb  = (const float*)d_in[8];
    const float* dis  = (const float*)d_in[9];
    const int*   ei0  = (const int*)d_in[10];
    const int*   ei1  = (const int*)d_in[11];
    const int*   bat0 = (const int*)d_in[12];
    const int*   bat1 = (const int*)d_in[13];
    const int*   ei2  = (const int*)d_in[14];

    const int N  = in_sizes[0] / IN_F;
    const int E  = in_sizes[10] / 2;
    const int B  = in_sizes[8] / (NEXP * EMB);
    const int E2 = in_sizes[14] / 2;

    float* gate_out = (float*)d_out;               // B*NEXP
    float* loss_out = gate_out + (size_t)B * NEXP; // 1

    // workspace layout
    float* ws      = (float*)d_ws;
    float* dinv    = ws;                           // N
    float* bufA    = dinv + N;                     // N*64  (xws1; then xws2|h2)
    float* bufB    = bufA + (size_t)N * 64;        // N*64  (h1)
    float* pooled0 = bufB + (size_t)N * 64;        // B*32
    float* pooled1 = pooled0 + (size_t)B * OUT_F;  // B*32
    float* cnt     = pooled1 + (size_t)B * OUT_F;  // B
    int*   iws     = (int*)(cnt + B);
    int*   counts  = iws;                          // N
    int*   offsets = counts + N;                   // N+1
    int*   cursor  = offsets + N + 1;              // N
    int*   csr_src = cursor + N;                   // E
    int*   lexcl   = csr_src + E;                  // N
    int*   partials= lexcl + N;                    // <=1024

    const int TB = 256;
    const int zgrid = 512;
    const int NB = (N + 1023) / 1024;              // scan blocks (<=1024)

    for (int g = 0; g < 2; ++g) {
        const float* x    = (g == 0) ? x0 : x1;
        const int* src    = (g == 0) ? ei0 : ei1;
        const int* dst    = src + E;
        const int* batch  = (g == 0) ? bat0 : bat1;
        float* pooled     = (g == 0) ? pooled0 : pooled1;

        float* xws1 = bufA;
        float* h1   = bufB;
        float* xws2 = bufA;                          // reuse (xws1 dead after agg1)
        float* h2   = bufA + (size_t)N * OUT_F;

        // CSR build (shared by both convs) + dinv
        zero_i32_kernel<<<zgrid, TB, 0, stream>>>(counts, N);
        hist_kernel<<<(E + TB - 1) / TB, TB, 0, stream>>>(dst, counts, E);
        scan1_kernel<<<NB, 1024, 0, stream>>>(counts, lexcl, partials, N);
        scan2_kernel<<<1, 1024, 0, stream>>>(partials, NB);
        scan3_kernel<<<(N + TB - 1) / TB, TB, 0, stream>>>(lexcl, partials, counts,
                                                           offsets, cursor, dinv, N, E);
        scatter_kernel<<<(E + TB - 1) / TB, TB, 0, stream>>>(src, dst, cursor, csr_src, E);

        // conv1: 64 -> 64
        gemm_selfloop_kernel<IN_F, HID_F, 4>
            <<<(N + 3) / 4, 4 * HID_F, 0, stream>>>(x, W1, b1, dinv, xws1, h1, N);
        csr_agg_kernel<HID_F>
            <<<(N + 3) / 4, TB, 0, stream>>>(csr_src, offsets, xws1, dinv, h1, N);

        // conv2: 64 -> 32
        gemm_selfloop_kernel<HID_F, OUT_F, 8>
            <<<(N + 7) / 8, 8 * OUT_F, 0, stream>>>(h1, W2, b2, dinv, xws2, h2, N);
        csr_agg_kernel<OUT_F>
            <<<(N + 7) / 8, TB, 0, stream>>>(csr_src, offsets, xws2, dinv, h2, N);

        // mean pool
        zero_f32_kernel<<<zgrid, TB, 0, stream>>>(pooled, (long long)B * OUT_F);
        zero_f32_kernel<<<zgrid, TB, 0, stream>>>(cnt, B);
        pool_sum_kernel<<<((N * 32) + TB - 1) / TB, TB, 0, stream>>>(h2, batch, pooled, cnt, N);
        pool_div_kernel<<<((B * OUT_F) + TB - 1) / TB, TB, 0, stream>>>(pooled, cnt, B);
    }

    // gate
    gate_kernel<<<(B + TB - 1) / TB, TB, 0, stream>>>(pooled0, pooled1, Wc, bc, gate_out, B);

    // distortion loss
    zero_scalar_kernel<<<1, 1, 0, stream>>>(loss_out);
    distortion_kernel<<<2048, TB, 0, stream>>>(emb, gate_out, dis,
                                               ei2, ei2 + E2, loss_out, E2);
}